// Round 1
// 2243.996 us; speedup vs baseline: 5.0771x; 5.0771x over previous
//
#include <hip/hip_runtime.h>
#include <stdint.h>

// Problem constants
#define B_      1024
#define T_      120
#define SENSORY 65
#define H_      512
#define RULE    64
#define NTASK   50
#define ENC_H   128
#define OUT_    33
#define IN_DIM  129     // RULE + SENSORY
#define G3      1536    // 3*H
#define INFO_DUR 20

// d_out layout (f32): out (B*T*33) | rnn_hid (B*T*512) | rule_enc (B*64)
#define OUT_ELEMS  (B_ * T_ * OUT_)
#define HID_ELEMS  (B_ * T_ * H_)
#define HID_OFF    OUT_ELEMS
#define RENC_OFF   (OUT_ELEMS + HID_ELEMS)

typedef __bf16 bf16;
typedef __bf16 bf16x8 __attribute__((ext_vector_type(8)));
typedef float  f32x4  __attribute__((ext_vector_type(4)));

#define MFMA_BF16(a, b, c) __builtin_amdgcn_mfma_f32_16x16x32_bf16((a), (b), (c), 0, 0, 0)

__device__ __forceinline__ float sigmoidf_(float x) {
    return 1.f / (1.f + __expf(-x));
}

// async global->LDS, 16B per lane; LDS dest = uniform base + lane*16
__device__ __forceinline__ void gload_lds16(const void* g, void* l) {
    __builtin_amdgcn_global_load_lds(
        (const __attribute__((address_space(1))) void*)g,
        (__attribute__((address_space(3))) void*)l, 16, 0, 0);
}

// ---------------------------------------------------------------------------
// Fragment-tile layout (shared by all MFMA kernels):
// A-side tile (mb, kb): 16 rows (m) x 32 k, slot s (0..63) = (kq*16 + row),
//   slot holds 8 bf16 = M[mb*16+row][kb*32 + kq*8 .. +7].  (1 KB per tile)
// MFMA lane l reads slot l  ->  row = l&15, k-slice = (l>>4)*8  (exact A-frag)
// B-side tile (nb, kb): same with n (W row) in place of m -> supplies W^T.
// ---------------------------------------------------------------------------

// K_init: h0 = 0.1 (f32 + bf16 hi/lo split buffers)
__global__ void init_h_kernel(float* __restrict__ h, bf16* __restrict__ hhi,
                              bf16* __restrict__ hlo) {
    int i = blockIdx.x * 256 + threadIdx.x;   // grid exact: B*H/256
    h[i] = 0.1f;
    bf16 hi = (bf16)0.1f;
    hhi[i] = hi;
    hlo[i] = (bf16)(0.1f - (float)hi);
}

// w_hh (1536x512 f32) -> frag tiles, tile index = kb*96 + nb  (kb<16, nb<96)
__global__ void whh_prep_kernel(const float* __restrict__ w,
                                bf16* __restrict__ whi, bf16* __restrict__ wlo) {
    int gid = blockIdx.x * 256 + threadIdx.x;       // [0, 16*96*64)
    int tile = gid >> 6, slot = gid & 63;
    int kb = tile / 96, nb = tile % 96;
    int n = nb * 16 + (slot & 15);
    int k = kb * 32 + (slot >> 4) * 8;
    const float* src = w + (size_t)n * H_ + k;
    bf16x8 hv, lv;
#pragma unroll
    for (int e = 0; e < 8; ++e) {
        float v = src[e];
        bf16 h = (bf16)v;
        hv[e] = h;
        lv[e] = (bf16)(v - (float)h);
    }
    *(bf16x8*)(whi + (size_t)gid * 8) = hv;
    *(bf16x8*)(wlo + (size_t)gid * 8) = lv;
}

// w_ih[:, 64:129] (x-part), K padded 65->128, tile = kb*96 + nb (kb<4, nb<96)
__global__ void wih_prep_kernel(const float* __restrict__ wih,
                                bf16* __restrict__ whi, bf16* __restrict__ wlo) {
    int gid = blockIdx.x * 256 + threadIdx.x;       // [0, 4*96*64)
    int tile = gid >> 6, slot = gid & 63;
    int kb = tile / 96, nb = tile % 96;
    int n = nb * 16 + (slot & 15);
    int s0 = kb * 32 + (slot >> 4) * 8;
    bf16x8 hv, lv;
#pragma unroll
    for (int e = 0; e < 8; ++e) {
        int s = s0 + e;
        float v = (s < SENSORY) ? wih[(size_t)n * IN_DIM + RULE + s] : 0.f;
        bf16 h = (bf16)v;
        hv[e] = h;
        lv[e] = (bf16)(v - (float)h);
    }
    *(bf16x8*)(whi + (size_t)gid * 8) = hv;
    *(bf16x8*)(wlo + (size_t)gid * 8) = lv;
}

// out_w (33x512), N padded 33->48, tile = kb*3 + nb (kb<16, nb<3)
__global__ void outw_prep_kernel(const float* __restrict__ ow,
                                 bf16* __restrict__ whi, bf16* __restrict__ wlo) {
    int gid = blockIdx.x * 256 + threadIdx.x;       // [0, 16*3*64)
    int tile = gid >> 6, slot = gid & 63;
    int kb = tile / 3, nb = tile % 3;
    int n = nb * 16 + (slot & 15);
    int k = kb * 32 + (slot >> 4) * 8;
    bf16x8 hv, lv;
#pragma unroll
    for (int e = 0; e < 8; ++e) {
        float v = (n < OUT_) ? ow[(size_t)n * H_ + k + e] : 0.f;
        bf16 h = (bf16)v;
        hv[e] = h;
        lv[e] = (bf16)(v - (float)h);
    }
    *(bf16x8*)(whi + (size_t)gid * 8) = hv;
    *(bf16x8*)(wlo + (size_t)gid * 8) = lv;
}

// ---------------------------------------------------------------------------
// encoder (unchanged)
__global__ void __launch_bounds__(128) enc_kernel(
    const float* __restrict__ task_rule, const float* __restrict__ rule_transform,
    const float* __restrict__ enc_w1, const float* __restrict__ enc_b1,
    const float* __restrict__ enc_w2, const float* __restrict__ enc_b2,
    float* __restrict__ renc_out)
{
    int b = blockIdx.x;
    int tid = threadIdx.x;
    __shared__ float tr_s[NTASK];
    __shared__ float rt_s[RULE];
    __shared__ float h1_s[ENC_H];

    if (tid < NTASK) tr_s[tid] = task_rule[b * NTASK + tid];
    __syncthreads();
    if (tid < RULE) {
        float acc = 0.f;
        for (int n = 0; n < NTASK; ++n)
            acc += tr_s[n] * rule_transform[n * RULE + tid];
        rt_s[tid] = acc;
    }
    __syncthreads();
    {
        float acc = 0.f;
        for (int k = 0; k < RULE; ++k)
            acc += rt_s[k] * enc_w1[tid * RULE + k];
        acc += enc_b1[tid];
        h1_s[tid] = fmaxf(acc, 0.f);
    }
    __syncthreads();
    if (tid < RULE) {
        float acc = 0.f;
        for (int i = 0; i < ENC_H; ++i)
            acc += h1_s[i] * enc_w2[tid * ENC_H + i];
        acc += enc_b2[tid];
        renc_out[b * RULE + tid] = fmaxf(acc, 0.f);
    }
}

// rule_gi[b][g] = renc[b][:64] . w_ih[g][:64]  (f32, unchanged)
__global__ void __launch_bounds__(256) rulegi_kernel(
    const float* __restrict__ renc, const float* __restrict__ w_ih,
    float* __restrict__ rule_gi)
{
    int id = blockIdx.x * 256 + threadIdx.x;
    int b = id / G3, g = id % G3;
    const float* r = renc + b * RULE;
    const float* w = w_ih + (size_t)g * IN_DIM;
    float acc = 0.f;
#pragma unroll 8
    for (int k = 0; k < RULE; ++k) acc += r[k] * w[k];
    rule_gi[id] = acc;
}

// ---------------------------------------------------------------------------
// GRU step, MFMA 16x16x32 bf16 with 3-term hi/lo split.
// Block tile: 32 batch x 32 j (x3 gates). 4 waves; wave = (mw = w&1 m-half,
// jw = w>>1 j-half), wave tile = 16b x 16j x 3 gates -> epilogue thread-local.
// K = 512 (h, 8 chunks of 64) + 128 (x padded, 2 chunks).
// LDS: A dbuf 2x8KB | B dbuf 2x24KB | AX 16KB = 80KB -> 2 blocks/CU.
__global__ void __launch_bounds__(256, 2) step_kernel(
    const float* __restrict__ h_src, int hs_stride,
    float* __restrict__ h_dst,
    const bf16* __restrict__ hin_hi, const bf16* __restrict__ hin_lo,
    bf16* __restrict__ hout_hi, bf16* __restrict__ hout_lo,
    const bf16* __restrict__ whh_hi, const bf16* __restrict__ whh_lo,
    const bf16* __restrict__ wih_hi, const bf16* __restrict__ wih_lo,
    const float* __restrict__ x, const float* __restrict__ rule_gi,
    const float* __restrict__ b_ih, const float* __restrict__ b_hh,
    int t)
{
    __shared__ __align__(16) unsigned char smem[81920];
    bf16* const A0 = (bf16*)smem;              // tiles: mbl + 2*kbl + 4*hh
    bf16* const Bm = (bf16*)(smem + 16384);    // tiles: nbl + 6*kbl + 12*hh
    bf16* const AX = (bf16*)(smem + 65536);    // tiles: mbl + 2*kbx + 8*hh

    const int tid  = threadIdx.x;
    const int w    = tid >> 6;
    const int lane = tid & 63;
    const int bx   = blockIdx.x;   // batch/32
    const int by   = blockIdx.y;   // j/32
    const int mw   = w & 1;
    const int jw   = w >> 1;

    f32x4 acc0 = {0.f, 0.f, 0.f, 0.f};   // r   (h-part + x-part)
    f32x4 acc1 = {0.f, 0.f, 0.f, 0.f};   // z   (h-part + x-part)
    f32x4 acc2 = {0.f, 0.f, 0.f, 0.f};   // h_n (h-part only)
    f32x4 acc3 = {0.f, 0.f, 0.f, 0.f};   // i_n (x-part only)

    // ---- build x fragments in LDS (zero-pad K 65->128, split hi/lo) ----
    {
        f32x4 z = {0.f, 0.f, 0.f, 0.f};
#pragma unroll
        for (int i = 0; i < 4; ++i)
            *(f32x4*)(smem + 65536 + (tid + i * 256) * 16) = z;
    }
    __syncthreads();
    for (int v = tid; v < 32 * SENSORY; v += 256) {
        int bl = v / SENSORY;
        int s  = v - bl * SENSORY;
        float xv = x[((size_t)(bx * 32 + bl) * T_ + t) * SENSORY + s];
        bf16 hi = (bf16)xv;
        bf16 lo = (bf16)(xv - (float)hi);
        int idx = ((bl >> 4) + 2 * (s >> 5)) * 512
                + (((s >> 3) & 3) * 16 + (bl & 15)) * 8 + (s & 7);
        AX[idx] = hi;
        AX[idx + 8 * 512] = lo;
    }

    // ---- staging: wave 0 -> A tiles (8), waves 1..3 -> B tiles (24) ----
    auto stageH = [&](int c, int buf) {
        if (w == 0) {
#pragma unroll
            for (int i = 0; i < 8; ++i) {
                const int mbl = i & 1, kbl = (i >> 1) & 1, hh = i >> 2;
                const bf16* src = (hh ? hin_lo : hin_hi)
                    + ((size_t)((2 * c + kbl) * 64 + bx * 2 + mbl)) * 512 + lane * 8;
                gload_lds16(src, A0 + buf * 4096 + i * 512);
            }
        } else {
#pragma unroll
            for (int i = 0; i < 8; ++i) {
                const int u = (w - 1) * 8 + i;
                const int nbl = u % 6, kbl = (u / 6) & 1, hh = u / 12;
                const int nb = (nbl >> 1) * 32 + by * 2 + (nbl & 1);
                const bf16* src = (hh ? whh_lo : whh_hi)
                    + ((size_t)((2 * c + kbl) * 96 + nb)) * 512 + lane * 8;
                gload_lds16(src, Bm + buf * 12288 + u * 512);
            }
        }
    };
    auto stageX = [&](int cx, int buf) {   // cx in {0,1}; only B (w_ih) tiles
        if (w > 0) {
#pragma unroll
            for (int i = 0; i < 8; ++i) {
                const int u = (w - 1) * 8 + i;
                const int nbl = u % 6, kbl = (u / 6) & 1, hh = u / 12;
                const int nb = (nbl >> 1) * 32 + by * 2 + (nbl & 1);
                const bf16* src = (hh ? wih_lo : wih_hi)
                    + ((size_t)((cx * 2 + kbl) * 96 + nb)) * 512 + lane * 8;
                gload_lds16(src, Bm + buf * 12288 + u * 512);
            }
        }
    };
    auto computeH = [&](int buf) {
#pragma unroll
        for (int kbl = 0; kbl < 2; ++kbl) {
            const bf16* ab = A0 + buf * 4096 + (mw + 2 * kbl) * 512 + lane * 8;
            const bf16x8 ahi = *(const bf16x8*)ab;
            const bf16x8 alo = *(const bf16x8*)(ab + 4 * 512);
            const bf16* bb = Bm + buf * 12288 + (jw + 6 * kbl) * 512 + lane * 8;
            {   const bf16x8 bhi = *(const bf16x8*)bb;
                const bf16x8 blo = *(const bf16x8*)(bb + 12 * 512);
                acc0 = MFMA_BF16(ahi, bhi, acc0);
                acc0 = MFMA_BF16(alo, bhi, acc0);
                acc0 = MFMA_BF16(ahi, blo, acc0); }
            {   const bf16x8 bhi = *(const bf16x8*)(bb + 2 * 512);
                const bf16x8 blo = *(const bf16x8*)(bb + 14 * 512);
                acc1 = MFMA_BF16(ahi, bhi, acc1);
                acc1 = MFMA_BF16(alo, bhi, acc1);
                acc1 = MFMA_BF16(ahi, blo, acc1); }
            {   const bf16x8 bhi = *(const bf16x8*)(bb + 4 * 512);
                const bf16x8 blo = *(const bf16x8*)(bb + 16 * 512);
                acc2 = MFMA_BF16(ahi, bhi, acc2);
                acc2 = MFMA_BF16(alo, bhi, acc2);
                acc2 = MFMA_BF16(ahi, blo, acc2); }
        }
    };
    auto computeX = [&](int cx, int buf) {
#pragma unroll
        for (int kbl = 0; kbl < 2; ++kbl) {
            const int kbx = cx * 2 + kbl;
            const bf16* ab = AX + (mw + 2 * kbx) * 512 + lane * 8;
            const bf16x8 ahi = *(const bf16x8*)ab;
            const bf16x8 alo = *(const bf16x8*)(ab + 8 * 512);
            const bf16* bb = Bm + buf * 12288 + (jw + 6 * kbl) * 512 + lane * 8;
            {   const bf16x8 bhi = *(const bf16x8*)bb;
                const bf16x8 blo = *(const bf16x8*)(bb + 12 * 512);
                acc0 = MFMA_BF16(ahi, bhi, acc0);
                acc0 = MFMA_BF16(alo, bhi, acc0);
                acc0 = MFMA_BF16(ahi, blo, acc0); }
            {   const bf16x8 bhi = *(const bf16x8*)(bb + 2 * 512);
                const bf16x8 blo = *(const bf16x8*)(bb + 14 * 512);
                acc1 = MFMA_BF16(ahi, bhi, acc1);
                acc1 = MFMA_BF16(alo, bhi, acc1);
                acc1 = MFMA_BF16(ahi, blo, acc1); }
            {   const bf16x8 bhi = *(const bf16x8*)(bb + 4 * 512);
                const bf16x8 blo = *(const bf16x8*)(bb + 16 * 512);
                acc3 = MFMA_BF16(ahi, bhi, acc3);
                acc3 = MFMA_BF16(alo, bhi, acc3);
                acc3 = MFMA_BF16(ahi, blo, acc3); }
        }
    };

    // ---- 2-phase double-buffered K loop: buf = chunk & 1 throughout ----
    stageH(0, 0);
    __syncthreads();
#pragma unroll
    for (int c = 0; c < 8; ++c) {
        if (c < 7) stageH(c + 1, (c + 1) & 1);
        else       stageX(0, 0);               // chunk 8 -> buf 0
        computeH(c & 1);
        __syncthreads();
    }
    stageX(1, 1);                              // chunk 9 -> buf 1
    computeX(0, 0);
    __syncthreads();
    computeX(1, 1);

    // ---- epilogue: gates + state update + bf16 split write (frag layout) ----
    const int jj  = by * 32 + jw * 16 + (lane & 15);
    const int bb0 = bx * 32 + mw * 16 + ((lane >> 4) << 2);
    const float bihr = b_ih[jj], bihz = b_ih[H_ + jj], bihn = b_ih[2 * H_ + jj];
    const float bhhr = b_hh[jj], bhhz = b_hh[H_ + jj], bhhn = b_hh[2 * H_ + jj];
    const bool use_rule = (t < INFO_DUR);
    const size_t tb = ((size_t)(by * 64 + bx * 2 + mw)) * 512;
    const int scol = ((jj >> 3) & 3) * 16;
#pragma unroll
    for (int r = 0; r < 4; ++r) {
        const int b = bb0 + r;
        float rg_r = 0.f, rg_z = 0.f, rg_n = 0.f;
        if (use_rule) {
            const float* rg = rule_gi + (size_t)b * G3 + jj;
            rg_r = rg[0]; rg_z = rg[H_]; rg_n = rg[2 * H_];
        }
        const float rr = sigmoidf_(acc0[r] + bihr + bhhr + rg_r);
        const float zz = sigmoidf_(acc1[r] + bihz + bhhz + rg_z);
        const float hn = acc2[r] + bhhn;
        const float in = acc3[r] + bihn + rg_n;
        const float nn = fmaxf(in + rr * hn, 0.f);
        const float ho = h_src[(size_t)b * hs_stride + jj];
        const float hnew = (1.f - zz) * nn + zz * ho;
        h_dst[(size_t)b * (T_ * H_) + jj] = hnew;   // rnn_hid[b][t][jj]
        const bf16 hi = (bf16)hnew;
        const bf16 lo = (bf16)(hnew - (float)hi);
        const size_t ha = tb + (size_t)(scol + (b & 15)) * 8 + (jj & 7);
        hout_hi[ha] = hi;
        hout_lo[ha] = lo;
    }
}

// ---------------------------------------------------------------------------
// out = sigmoid(hid @ out_w^T + b): MFMA, N padded 33->48, 64 rows/block.
// A tiles built in-kernel from f32 hid (hi/lo split); B from pre-tiled out_w.
__global__ void __launch_bounds__(256) out_kernel(
    const float* __restrict__ hid,
    const bf16* __restrict__ owhi, const bf16* __restrict__ owlo,
    const float* __restrict__ out_b, float* __restrict__ out)
{
    __shared__ __align__(16) unsigned char smem[28672];
    bf16* const A  = (bf16*)smem;            // 16 tiles: mbl + 4*kbl + 8*hh
    bf16* const Bf = (bf16*)(smem + 16384);  // 12 tiles: nbl + 3*kbl + 6*hh
    const int tid = threadIdx.x, w = tid >> 6, lane = tid & 63;
    const int bt0 = blockIdx.x * 64;

    f32x4 acc0 = {0.f, 0.f, 0.f, 0.f};
    f32x4 acc1 = {0.f, 0.f, 0.f, 0.f};
    f32x4 acc2 = {0.f, 0.f, 0.f, 0.f};

#pragma unroll 1
    for (int c = 0; c < 8; ++c) {            // K chunks of 64
        __syncthreads();
        // stage B (12 x 1KB tiles, coalesced)
#pragma unroll
        for (int i = 0; i < 3; ++i) {
            const int u = w * 3 + i;
            const int nbl = u % 3, kbl = (u / 3) & 1, hh = u / 6;
            const bf16* src = (hh ? owlo : owhi)
                + ((size_t)((2 * c + kbl) * 3 + nbl)) * 512 + lane * 8;
            gload_lds16(src, Bf + u * 512);
        }
        // stage A: f32 -> bf16 hi/lo frags
#pragma unroll
        for (int it = 0; it < 2; ++it) {
            const int v = tid + it * 256;
            const int row = v >> 3, kq = v & 7;
            const float* src = hid + (size_t)(bt0 + row) * H_ + c * 64 + kq * 8;
            const f32x4 v0 = *(const f32x4*)src;
            const f32x4 v1 = *(const f32x4*)(src + 4);
            bf16x8 hv, lv;
#pragma unroll
            for (int e = 0; e < 4; ++e) {
                bf16 h0 = (bf16)v0[e]; hv[e] = h0;     lv[e] = (bf16)(v0[e] - (float)h0);
                bf16 h1 = (bf16)v1[e]; hv[4 + e] = h1; lv[4 + e] = (bf16)(v1[e] - (float)h1);
            }
            const int at = (row >> 4) + 4 * (kq >> 2);
            const int sl = ((kq & 3) * 16 + (row & 15)) * 8;
            *(bf16x8*)(A + at * 512 + sl) = hv;
            *(bf16x8*)(A + (at + 8) * 512 + sl) = lv;
        }
        __syncthreads();
#pragma unroll
        for (int kbl = 0; kbl < 2; ++kbl) {
            const bf16* ab = A + (w + 4 * kbl) * 512 + lane * 8;
            const bf16x8 ahi = *(const bf16x8*)ab;
            const bf16x8 alo = *(const bf16x8*)(ab + 8 * 512);
            const bf16* bb = Bf + (3 * kbl) * 512 + lane * 8;
            {   const bf16x8 bhi = *(const bf16x8*)bb;
                const bf16x8 blo = *(const bf16x8*)(bb + 6 * 512);
                acc0 = MFMA_BF16(ahi, bhi, acc0);
                acc0 = MFMA_BF16(alo, bhi, acc0);
                acc0 = MFMA_BF16(ahi, blo, acc0); }
            {   const bf16x8 bhi = *(const bf16x8*)(bb + 512);
                const bf16x8 blo = *(const bf16x8*)(bb + 7 * 512);
                acc1 = MFMA_BF16(ahi, bhi, acc1);
                acc1 = MFMA_BF16(alo, bhi, acc1);
                acc1 = MFMA_BF16(ahi, blo, acc1); }
            {   const bf16x8 bhi = *(const bf16x8*)(bb + 2 * 512);
                const bf16x8 blo = *(const bf16x8*)(bb + 8 * 512);
                acc2 = MFMA_BF16(ahi, bhi, acc2);
                acc2 = MFMA_BF16(alo, bhi, acc2);
                acc2 = MFMA_BF16(ahi, blo, acc2); }
        }
    }
    const int col = lane & 15, rb = (lane >> 4) * 4;
#pragma unroll
    for (int nb = 0; nb < 3; ++nb) {
        const int o = nb * 16 + col;
        if (o < OUT_) {
            const float ob = out_b[o];
            const f32x4 a = (nb == 0) ? acc0 : (nb == 1) ? acc1 : acc2;
#pragma unroll
            for (int r = 0; r < 4; ++r) {
                const int row = bt0 + w * 16 + rb + r;
                out[(size_t)row * OUT_ + o] = sigmoidf_(a[r] + ob);
            }
        }
    }
}

// ---------------------------------------------------------------------------
extern "C" void kernel_launch(void* const* d_in, const int* in_sizes, int n_in,
                              void* d_out, int out_size, void* d_ws, size_t ws_size,
                              hipStream_t stream)
{
    const float* x              = (const float*)d_in[0];
    const float* task_rule      = (const float*)d_in[1];
    const float* rule_transform = (const float*)d_in[2];
    const float* enc_w1         = (const float*)d_in[3];
    const float* enc_b1         = (const float*)d_in[4];
    const float* enc_w2         = (const float*)d_in[5];
    const float* enc_b2         = (const float*)d_in[6];
    const float* w_ih           = (const float*)d_in[7];
    const float* w_hh           = (const float*)d_in[8];
    const float* b_ih           = (const float*)d_in[9];
    const float* b_hh           = (const float*)d_in[10];
    const float* out_w          = (const float*)d_in[11];
    const float* out_b          = (const float*)d_in[12];

    float* out_p  = (float*)d_out;
    float* hid_p  = (float*)d_out + HID_OFF;
    float* renc_p = (float*)d_out + RENC_OFF;

    // workspace layout (bytes), total 16,613,376
    uint8_t* wsb = (uint8_t*)d_ws;
    float* rule_gi = (float*)(wsb + 0);           // B*G3*4      = 6,291,456
    float* hinit   = (float*)(wsb + 6291456);     // B*H*4       = 2,097,152
    bf16* h_hi[2]  = { (bf16*)(wsb + 8388608),    // 4 x B*H*2   = 4,194,304
                       (bf16*)(wsb + 10485760) };
    bf16* h_lo[2]  = { (bf16*)(wsb + 9437184),
                       (bf16*)(wsb + 11534336) };
    bf16* whhhi = (bf16*)(wsb + 12582912);        // G3*H*2      = 1,572,864
    bf16* whhlo = (bf16*)(wsb + 14155776);
    bf16* wihhi = (bf16*)(wsb + 15728640);        // G3*128*2    =   393,216
    bf16* wihlo = (bf16*)(wsb + 16121856);
    bf16* owhi  = (bf16*)(wsb + 16515072);        // 48*512*2    =    49,152
    bf16* owlo  = (bf16*)(wsb + 16564224);

    init_h_kernel<<<(B_ * H_) / 256, 256, 0, stream>>>(hinit, h_hi[0], h_lo[0]);
    whh_prep_kernel<<<384, 256, 0, stream>>>(w_hh, whhhi, whhlo);
    wih_prep_kernel<<<96, 256, 0, stream>>>(w_ih, wihhi, wihlo);
    outw_prep_kernel<<<12, 256, 0, stream>>>(out_w, owhi, owlo);
    enc_kernel<<<B_, 128, 0, stream>>>(task_rule, rule_transform, enc_w1, enc_b1,
                                       enc_w2, enc_b2, renc_p);
    rulegi_kernel<<<(B_ * G3) / 256, 256, 0, stream>>>(renc_p, w_ih, rule_gi);

    for (int t = 0; t < T_; ++t) {
        const float* hs = (t == 0) ? hinit : (hid_p + (size_t)(t - 1) * H_);
        int stride      = (t == 0) ? H_ : (T_ * H_);
        float* hd       = hid_p + (size_t)t * H_;
        const int pi = t & 1, po = (t + 1) & 1;
        step_kernel<<<dim3(B_ / 32, H_ / 32), 256, 0, stream>>>(
            hs, stride, hd, h_hi[pi], h_lo[pi], h_hi[po], h_lo[po],
            whhhi, whhlo, wihhi, wihlo, x, rule_gi, b_ih, b_hh, t);
    }

    out_kernel<<<(B_ * T_) / 64, 256, 0, stream>>>(hid_p, owhi, owlo, out_b, out_p);
}